// Round 5
// baseline (1354.273 us; speedup 1.0000x reference)
//
#include <hip/hip_runtime.h>
#include <math.h>

#define NN 4096
#define BB 4
#define KK 20
#define OUTC 256
#define GN (BB*NN)

// ---------------- xx[b][n] = sum_c x[b][c][n]^2 ----------------
template<int C>
__global__ void __launch_bounds__(256) xx_kernel(const float* __restrict__ x, int bstride,
                                                 float* __restrict__ xxo) {
  int i = blockIdx.x*256 + threadIdx.x;
  int b = i >> 12, n = i & (NN-1);
  const float* xp = x + (size_t)b*bstride + n;
  float s = 0.f;
#pragma unroll
  for (int c = 0; c < C; ++c) { float v = xp[(size_t)c*NN]; s = fmaf(v, v, s); }
  xxo[i] = s;
}

__device__ __forceinline__ unsigned ord_u32(float v) {
  unsigned b = __float_as_uint(v);
  return (b & 0x80000000u) ? ~b : (b | 0x80000000u);
}

// Exact top-KK extraction from 64 lanes x S register slots via ballot bit-bisect.
// Order semantics: (value desc, idx asc) == jax.lax.top_k. Emits the index SET
// (downstream sum/max over k is order-invariant). Returns per-lane count kept.
template<int S>
__device__ __forceinline__ int extract_top20(const float (&sv)[S], const int (&si)[S],
                                             int* __restrict__ outp,
                                             unsigned long long lmask) {
  unsigned u[S];
#pragma unroll
  for (int k = 0; k < S; ++k) u[k] = ord_u32(sv[k]);
  // value bisect: largest T with count(u >= T) >= KK  -> T = 20th-largest value
  unsigned T = 0u;
#pragma unroll 1
  for (int bit = 31; bit >= 0; --bit) {
    unsigned Tp = T | (1u << bit);
    int c = 0;
#pragma unroll
    for (int k = 0; k < S; ++k) c += __popcll(__ballot(u[k] >= Tp));
    if (c >= KK) T = Tp;
  }
  int cgt = 0;
#pragma unroll
  for (int k = 0; k < S; ++k) cgt += __popcll(__ballot(u[k] > T));
  const int r = KK - cgt;  // how many value-ties to keep (smallest idx first)
  // idx bisect among equals: largest A with count(eq && idx < A) < r -> A = r-th smallest idx
  int A = 0;
#pragma unroll 1
  for (int bit = 11; bit >= 0; --bit) {
    int Ap = A | (1 << bit);
    int c = 0;
#pragma unroll
    for (int k = 0; k < S; ++k) c += __popcll(__ballot(u[k] == T && si[k] < Ap));
    if (c < r) A = Ap;
  }
  // emit: val > T, or val == T && idx <= A   (exactly KK entries)
  int base = 0, nk = 0;
#pragma unroll
  for (int k = 0; k < S; ++k) {
    bool kp = (u[k] > T) || (u[k] == T && si[k] <= A);
    unsigned long long mk = __ballot(kp);
    int pos = base + __popcll(mk & lmask);
    if (kp) outp[pos] = si[k];
    base += __popcll(mk);
    nk += kp ? 1 : 0;
  }
  return nk;
}

// ---------------- KNN: 8 queries/wave, top-4/lane cascade + ballot-bisect extract ------
// Block = 256 thr = 4 waves; wave owns 8 queries -> 32 queries/block, grid = GN/32.
// Tiles of 512 candidates; lane's 8 m per tile: lane*4+{0..3} and 256+lane*4+{0..3}.
// Per c: 2 scatter ds_read_b128 (cand) + 2 uniform b128 (q) feed 64 FMA.
// Distance fma chain order identical to the validated R1..R4 kernels.
// Exactness: if a lane contributes all 4 slots to the top-20, flag query for cleanup.
template<int C>
__global__ void __launch_bounds__(256, 3) knn3_kernel(const float* __restrict__ x, int bstride,
                                                      const float* __restrict__ xxb,
                                                      int* __restrict__ idx_out,
                                                      int* __restrict__ flag_cnt,
                                                      int* __restrict__ flag_list) {
  constexpr int CC = (C < 16) ? C : 16;
  constexpr int S = 4;
  __shared__ float cand[CC][512];
  __shared__ float q_lds[CC][32];
  __shared__ float xm_lds[512];
  __shared__ float xq_lds[32];
  const int tid = threadIdx.x;
  const int wq = tid >> 6, lane = tid & 63;
  const unsigned long long lmask = (1ull << lane) - 1ull;
  const int qb = blockIdx.x;
  const int b = qb >> 7, n0 = (qb & 127) << 5;
  const float* xb  = x + (size_t)b*bstride;
  const float* xxr = xxb + b*NN;

  if (tid < 32) xq_lds[tid] = xxr[n0 + tid];
  __syncthreads();
  float xq[8];
#pragma unroll
  for (int i = 0; i < 8; ++i) xq[i] = xq_lds[wq*8 + i];

  float sv[8][S]; int si[8][S];
#pragma unroll
  for (int i = 0; i < 8; ++i)
#pragma unroll
    for (int k = 0; k < S; ++k) { sv[i][k] = -INFINITY; si[i][k] = 0x7fffffff; }

  for (int t = 0; t < NN/512; ++t) {
    const int mt0 = t*512;
    float acc[8][8];
#pragma unroll
    for (int i = 0; i < 8; ++i)
#pragma unroll
      for (int j = 0; j < 8; ++j) acc[i][j] = 0.f;

    for (int cc0 = 0; cc0 < C; cc0 += CC) {
      __syncthreads();
      for (int v = tid; v < CC*128; v += 256) {
        int c = v >> 7, mc = (v & 127) * 4;
        *reinterpret_cast<float4*>(&cand[c][mc]) =
          *reinterpret_cast<const float4*>(&xb[(size_t)(cc0 + c)*NN + mt0 + mc]);
      }
      for (int v = tid; v < CC*32; v += 256) {
        int c = v >> 5, qi = v & 31;
        q_lds[c][qi] = xb[(size_t)(cc0 + c)*NN + n0 + qi];
      }
      if (cc0 == 0 && tid < 128)
        *reinterpret_cast<float4*>(&xm_lds[tid*4]) =
          *reinterpret_cast<const float4*>(&xxr[mt0 + tid*4]);
      __syncthreads();
#pragma unroll 8
      for (int c = 0; c < CC; ++c) {
        float4 qa  = *reinterpret_cast<const float4*>(&q_lds[c][wq*8]);     // uniform -> broadcast
        float4 qb2 = *reinterpret_cast<const float4*>(&q_lds[c][wq*8 + 4]); // uniform -> broadcast
        float4 ca  = *reinterpret_cast<const float4*>(&cand[c][lane*4]);
        float4 cb  = *reinterpret_cast<const float4*>(&cand[c][256 + lane*4]);
        float qq[8] = {qa.x, qa.y, qa.z, qa.w, qb2.x, qb2.y, qb2.z, qb2.w};
        float mm[8] = {ca.x, ca.y, ca.z, ca.w, cb.x, cb.y, cb.z, cb.w};
#pragma unroll
        for (int i = 0; i < 8; ++i)
#pragma unroll
          for (int j = 0; j < 8; ++j) acc[i][j] = fmaf(qq[i], mm[j], acc[i][j]);
      }
    }

    float4 xma = *reinterpret_cast<const float4*>(&xm_lds[lane*4]);
    float4 xmb = *reinterpret_cast<const float4*>(&xm_lds[256 + lane*4]);
    float xmv[8] = {xma.x, xma.y, xma.z, xma.w, xmb.x, xmb.y, xmb.z, xmb.w};

#pragma unroll
    for (int i = 0; i < 8; ++i) {
#pragma unroll
      for (int j = 0; j < 8; ++j) {
        const float d = 2.f*acc[i][j] - xq[i] - xmv[j];
        const int mi = mt0 + ((j < 4) ? (lane*4 + j) : (256 + lane*4 + (j - 4)));
        // branchless sorted insert (desc; strict > keeps earlier=smaller idx first on ties)
        bool c0 = d > sv[i][0], c1 = d > sv[i][1], c2 = d > sv[i][2], c3 = d > sv[i][3];
        sv[i][3] = c2 ? sv[i][2] : (c3 ? d : sv[i][3]);  si[i][3] = c2 ? si[i][2] : (c3 ? mi : si[i][3]);
        sv[i][2] = c1 ? sv[i][1] : (c2 ? d : sv[i][2]);  si[i][2] = c1 ? si[i][1] : (c2 ? mi : si[i][2]);
        sv[i][1] = c0 ? sv[i][0] : (c1 ? d : sv[i][1]);  si[i][1] = c0 ? si[i][0] : (c1 ? mi : si[i][1]);
        sv[i][0] = c0 ? d : sv[i][0];                    si[i][0] = c0 ? mi : si[i][0];
      }
    }
  }

  // extraction: fully unrolled over the 8 queries (static register indexing)
#pragma unroll
  for (int i = 0; i < 8; ++i) {
    const int q = n0 + wq*8 + i;
    int* outp = idx_out + (size_t)(b*NN + q)*KK;
    int nk = extract_top20<S>(sv[i], si[i], outp, lmask);
    if (__ballot(nk >= S)) {
      if (lane == 0) { int p = atomicAdd(flag_cnt, 1); flag_list[p & 4095] = b*NN + q; }
    }
  }
}

// ---------------- exact cleanup for flagged queries (rare; ~1 block per query) ------
template<int C>
__global__ void __launch_bounds__(256) knn_fix_kernel(const float* __restrict__ x, int bstride,
                                                      const float* __restrict__ xxb,
                                                      const int* __restrict__ flag_cnt,
                                                      const int* __restrict__ flag_list,
                                                      int* __restrict__ idx_out) {
  __shared__ float redv[4]; __shared__ int redi[4];
  const int tid = threadIdx.x;
  const int wid = tid >> 6, lane = tid & 63;
  const int cnt = flag_cnt[0] < 4096 ? flag_cnt[0] : 4096;
  for (int f = blockIdx.x; f < cnt; f += gridDim.x) {
    const int qn = flag_list[f];
    const int b = qn >> 12, n = qn & (NN-1);
    const float* xb  = x + (size_t)b*bstride;
    const float* xxr = xxb + b*NN;
    float acc[16];
#pragma unroll
    for (int jj = 0; jj < 16; ++jj) acc[jj] = 0.f;
    for (int c = 0; c < C; ++c) {
      const float qc = xb[(size_t)c*NN + n];
      const float* row = xb + (size_t)c*NN + tid;
#pragma unroll
      for (int jj = 0; jj < 16; ++jj) acc[jj] = fmaf(qc, row[256*jj], acc[jj]);
    }
    const float xq = xxr[n];
    float dv[16]; int di[16]; unsigned used = 0;
#pragma unroll
    for (int jj = 0; jj < 16; ++jj) {
      dv[jj] = 2.f*acc[jj] - xq - xxr[tid + 256*jj];
      di[jj] = tid + 256*jj;
    }
    for (int r = 0; r < KK; ++r) {
      float bv = -INFINITY; int bi = 0x7fffffff;
#pragma unroll
      for (int jj = 0; jj < 16; ++jj) {
        bool ok = !((used >> jj) & 1);
        bool bet = ok && (dv[jj] > bv || (dv[jj] == bv && di[jj] < bi));
        bv = bet ? dv[jj] : bv; bi = bet ? di[jj] : bi;
      }
#pragma unroll
      for (int s = 1; s < 64; s <<= 1) {
        float ov = __shfl_xor(bv, s, 64);
        int   oi = __shfl_xor(bi, s, 64);
        if (ov > bv || (ov == bv && oi < bi)) { bv = ov; bi = oi; }
      }
      if (lane == 0) { redv[wid] = bv; redi[wid] = bi; }
      __syncthreads();
#pragma unroll
      for (int w = 0; w < 4; ++w) {
        float ov = redv[w]; int oi = redi[w];
        if (ov > bv || (ov == bv && oi < bi)) { bv = ov; bi = oi; }
      }
      __syncthreads();
      if ((bi & 255) == tid) used |= 1u << (bi >> 8);
      if (tid == 0) idx_out[(size_t)qn*KK + r] = bi;
    }
  }
}

// ---------------- P = W1 . x,  Q = (W2-W1) . x   (both [b][n][o]) ----------------
template<int C, int O>
__global__ void __launch_bounds__(256) pq_kernel(const float* __restrict__ x, int bstride,
                                                 const float* __restrict__ W,
                                                 float* __restrict__ P, float* __restrict__ Q) {
  constexpr int CC = (C < 32) ? C : 32;
  constexpr int NPP = 256 / O;
  constexpr int NITER = 64 / NPP;
  __shared__ float xt[C*64];
  __shared__ float w1t[CC*O];
  __shared__ float wdt[CC*O];
  const int tid = threadIdx.x;
  const int g0 = blockIdx.x*64;
  const int b = g0 >> 12, n0 = g0 & (NN-1);
  for (int i = tid; i < C*64; i += 256) {
    int c = i >> 6, j = i & 63;
    xt[i] = x[(size_t)b*bstride + (size_t)c*NN + (n0 + j)];
  }
  const int o = tid % O;
  const int ns = tid / O;
  float ap[NITER], aq[NITER];
#pragma unroll
  for (int i = 0; i < NITER; ++i) { ap[i] = 0.f; aq[i] = 0.f; }
  for (int cc = 0; cc < C; cc += CC) {
    __syncthreads();
    for (int i = tid; i < CC*O; i += 256) {
      int oo = i % O, c = i / O;
      float w1 = W[oo*(2*C) + cc + c];
      float w2 = W[oo*(2*C) + C + cc + c];
      w1t[c*O + oo] = w1;
      wdt[c*O + oo] = w2 - w1;
    }
    __syncthreads();
#pragma unroll
    for (int np = 0; np < NITER; ++np) {
      const int nl = np*NPP + ns;
#pragma unroll
      for (int c = 0; c < CC; ++c) {
        float xv = xt[(cc + c)*64 + nl];
        ap[np] = fmaf(xv, w1t[c*O + o], ap[np]);
        aq[np] = fmaf(xv, wdt[c*O + o], aq[np]);
      }
    }
  }
#pragma unroll
  for (int np = 0; np < NITER; ++np) {
    const int nl = np*NPP + ns;
    size_t row = (size_t)(g0 + nl)*O + o;
    P[row] = ap[np];
    Q[row] = aq[np];
  }
}

// ---------------- y = P[m]+Q[n]: per-(b,n,o) max/min over k + per-channel partial sums ----
template<int O>
__global__ void __launch_bounds__(256) stats_kernel(const float* __restrict__ P,
                                                    const float* __restrict__ Q,
                                                    const int* __restrict__ idxb,
                                                    float* __restrict__ ymax,
                                                    float* __restrict__ ymin,
                                                    float* __restrict__ parts) {
  constexpr int NPB = 256 / O;
  __shared__ float ls[256], ls2[256];
  const int tid = threadIdx.x;
  const int o = tid % O, ns = tid / O;
  const int g = blockIdx.x*NPB + ns;
  const int b = g >> 12;
  const float qvv = Q[(size_t)g*O + o];
  const int* ip = idxb + (size_t)g*KK;
  const float* Pb = P + (size_t)b*NN*O;
  float s = 0.f, s2 = 0.f, mx = -INFINITY, mn = INFINITY;
#pragma unroll 4
  for (int k = 0; k < KK; ++k) {
    int m = ip[k];
    float yv = Pb[(size_t)m*O + o] + qvv;
    s += yv; s2 = fmaf(yv, yv, s2);
    mx = fmaxf(mx, yv); mn = fminf(mn, yv);
  }
  ymax[(size_t)g*O + o] = mx;
  ymin[(size_t)g*O + o] = mn;
  ls[tid] = s; ls2[tid] = s2;
  __syncthreads();
  if (ns == 0) {
#pragma unroll
    for (int j = 1; j < NPB; ++j) { s += ls[j*O + o]; s2 += ls2[j*O + o]; }
    parts[(size_t)blockIdx.x*2*O + o] = s;
    parts[(size_t)blockIdx.x*2*O + O + o] = s2;
  }
}

// ---------------- per-channel BN affine coefficients (deterministic f64 tree) ----------
template<int O>
__global__ void __launch_bounds__(256) reduce_kernel(const float* __restrict__ parts, int nblocks,
                                                     const float* __restrict__ gg,
                                                     const float* __restrict__ bbp,
                                                     float* __restrict__ chan) {
  __shared__ double sh[512];
  const int o = blockIdx.x, t = threadIdx.x;
  double S = 0.0, S2 = 0.0;
  for (int i = t; i < nblocks; i += 256) {
    S  += (double)parts[(size_t)i*2*O + o];
    S2 += (double)parts[(size_t)i*2*O + O + o];
  }
  sh[t] = S; sh[256+t] = S2;
  __syncthreads();
  for (int s = 128; s > 0; s >>= 1) {
    if (t < s) { sh[t] += sh[t+s]; sh[256+t] += sh[256+t+s]; }
    __syncthreads();
  }
  if (t == 0) {
    const double M = (double)BB*NN*KK;
    double mean = sh[0]/M;
    double var  = sh[256]/M - mean*mean;
    double inv  = 1.0/sqrt(var + 1e-5);
    double A  = (double)gg[o]*inv;
    double Bc = (double)bbp[o] - mean*A;
    chan[2*o]   = (float)A;
    chan[2*o+1] = (float)Bc;
  }
}

// ---------------- out[b][cbase+o][n] = leaky(A*(A>0?ymax:ymin)+Bc), LDS transpose ------
template<int O>
__global__ void __launch_bounds__(256) final_kernel(const float* __restrict__ ymax,
                                                    const float* __restrict__ ymin,
                                                    const float* __restrict__ chan,
                                                    float* __restrict__ out, int cbase) {
  __shared__ float buf[64*(O+1)];
  const int tid = threadIdx.x;
  const int g0 = blockIdx.x*64;
  const int b = g0 >> 12, n0 = g0 & (NN-1);
  for (int i = tid; i < 64*O; i += 256) {
    int o = i % O, nl = i / O;
    size_t r = (size_t)(g0 + nl)*O + o;
    float A = chan[2*o], Bc = chan[2*o+1];
    float v = (A > 0.f) ? ymax[r] : ymin[r];
    float y = fmaf(A, v, Bc);
    buf[nl*(O+1) + o] = (y > 0.f) ? y : 0.2f*y;
  }
  __syncthreads();
  for (int i = tid; i < 64*O; i += 256) {
    int nl = i & 63, o = i >> 6;
    out[(size_t)b*(OUTC*NN) + (size_t)(cbase + o)*NN + (n0 + nl)] = buf[nl*(O+1) + o];
  }
}

extern "C" void kernel_launch(void* const* d_in, const int* in_sizes, int n_in,
                              void* d_out, int out_size, void* d_ws, size_t ws_size,
                              hipStream_t stream) {
  (void)in_sizes; (void)n_in; (void)out_size; (void)ws_size;
  const float* x  = (const float*)d_in[0];
  const float* W0 = (const float*)d_in[1];
  const float* g0 = (const float*)d_in[2];
  const float* b0 = (const float*)d_in[3];
  const float* W1 = (const float*)d_in[4];
  const float* g1 = (const float*)d_in[5];
  const float* b1 = (const float*)d_in[6];
  const float* W2 = (const float*)d_in[7];
  const float* g2 = (const float*)d_in[8];
  const float* b2 = (const float*)d_in[9];
  float* out = (float*)d_out;
  char* ws = (char*)d_ws;

  float* xxb  = (float*)(ws);                       // 64 KB
  int*   idxb = (int*)  (ws + ((size_t)1<<20));     // 1.31 MB
  float* P    = (float*)(ws + ((size_t)4<<20));     // 8 MB
  float* Q    = (float*)(ws + ((size_t)12<<20));    // 8 MB
  float* ymax = (float*)(ws + ((size_t)20<<20));    // 8 MB
  float* ymin = (float*)(ws + ((size_t)28<<20));    // 8 MB
  float* prts = (float*)(ws + ((size_t)36<<20));    // 8 MB
  float* chan = (float*)(ws + ((size_t)44<<20));    // 1 KB
  int*   fcnt = (int*)  (ws + ((size_t)45<<20));    // 3 ints
  int*   flst = (int*)  (ws + ((size_t)45<<20) + 64); // 3*4096 ints

  hipMemsetAsync(fcnt, 0, 3*sizeof(int), stream);

  // ---- layer 0: C=3 -> O=64, out channels [0,64) ----
  xx_kernel<3><<<GN/256, 256, 0, stream>>>(x, 3*NN, xxb);
  knn3_kernel<3><<<GN/32, 256, 0, stream>>>(x, 3*NN, xxb, idxb, fcnt+0, flst+0*4096);
  knn_fix_kernel<3><<<64, 256, 0, stream>>>(x, 3*NN, xxb, fcnt+0, flst+0*4096, idxb);
  pq_kernel<3,64><<<GN/64, 256, 0, stream>>>(x, 3*NN, W0, P, Q);
  stats_kernel<64><<<GN/4, 256, 0, stream>>>(P, Q, idxb, ymax, ymin, prts);
  reduce_kernel<64><<<64, 256, 0, stream>>>(prts, GN/4, g0, b0, chan);
  final_kernel<64><<<GN/64, 256, 0, stream>>>(ymax, ymin, chan, out, 0);

  // ---- layer 1: C=64 -> O=64, input = out[:,0:64,:], out channels [64,128) ----
  const float* x1 = out;
  xx_kernel<64><<<GN/256, 256, 0, stream>>>(x1, OUTC*NN, xxb);
  knn3_kernel<64><<<GN/32, 256, 0, stream>>>(x1, OUTC*NN, xxb, idxb, fcnt+1, flst+1*4096);
  knn_fix_kernel<64><<<64, 256, 0, stream>>>(x1, OUTC*NN, xxb, fcnt+1, flst+1*4096, idxb);
  pq_kernel<64,64><<<GN/64, 256, 0, stream>>>(x1, OUTC*NN, W1, P, Q);
  stats_kernel<64><<<GN/4, 256, 0, stream>>>(P, Q, idxb, ymax, ymin, prts);
  reduce_kernel<64><<<64, 256, 0, stream>>>(prts, GN/4, g1, b1, chan);
  final_kernel<64><<<GN/64, 256, 0, stream>>>(ymax, ymin, chan, out, 64);

  // ---- layer 2: C=64 -> O=128, input = out[:,64:128,:], out channels [128,256) ----
  const float* x2 = out + (size_t)64*NN;
  xx_kernel<64><<<GN/256, 256, 0, stream>>>(x2, OUTC*NN, xxb);
  knn3_kernel<64><<<GN/32, 256, 0, stream>>>(x2, OUTC*NN, xxb, idxb, fcnt+2, flst+2*4096);
  knn_fix_kernel<64><<<64, 256, 0, stream>>>(x2, OUTC*NN, xxb, fcnt+2, flst+2*4096, idxb);
  pq_kernel<64,128><<<GN/64, 256, 0, stream>>>(x2, OUTC*NN, W2, P, Q);
  stats_kernel<128><<<GN/2, 256, 0, stream>>>(P, Q, idxb, ymax, ymin, prts);
  reduce_kernel<128><<<128, 256, 0, stream>>>(prts, GN/2, g2, b2, chan);
  final_kernel<128><<<GN/64, 256, 0, stream>>>(ymax, ymin, chan, out, 128);
}

// Round 6
// 810.493 us; speedup vs baseline: 1.6709x; 1.6709x over previous
//
#include <hip/hip_runtime.h>
#include <math.h>

#define NN 4096
#define BB 4
#define KK 20
#define OUTC 256
#define GN (BB*NN)

// ---------------- xx[b][n] = sum_c x[b][c][n]^2 ----------------
template<int C>
__global__ void __launch_bounds__(256) xx_kernel(const float* __restrict__ x, int bstride,
                                                 float* __restrict__ xxo) {
  int i = blockIdx.x*256 + threadIdx.x;
  int b = i >> 12, n = i & (NN-1);
  const float* xp = x + (size_t)b*bstride + n;
  float s = 0.f;
#pragma unroll
  for (int c = 0; c < C; ++c) { float v = xp[(size_t)c*NN]; s = fmaf(v, v, s); }
  xxo[i] = s;
}

__device__ __forceinline__ unsigned ord_u32(float v) {
  unsigned b = __float_as_uint(v);
  return (b & 0x80000000u) ? ~b : (b | 0x80000000u);
}

// Exact top-KK extraction from 64 lanes x S register slots via ballot bit-bisect.
// Order semantics: (value desc, idx asc) == jax.lax.top_k. Emits the index SET
// (downstream sum/max over k is order-invariant). Returns true iff this query
// needs the exact-cleanup pass: some lane dropped a value od that could have
// belonged to the true top-20 (ord(od) >= T, conservative on exact ties).
template<int S>
__device__ __forceinline__ bool extract_top20(const float (&sv)[S], const int (&si)[S],
                                              float od, int* __restrict__ outp,
                                              unsigned long long lmask) {
  unsigned u[S];
#pragma unroll
  for (int k = 0; k < S; ++k) u[k] = ord_u32(sv[k]);
  // value bisect: largest T with count(u >= T) >= KK  -> T = 20th-largest value
  unsigned T = 0u;
#pragma unroll 1
  for (int bit = 31; bit >= 0; --bit) {
    unsigned Tp = T | (1u << bit);
    int c = 0;
#pragma unroll
    for (int k = 0; k < S; ++k) c += __popcll(__ballot(u[k] >= Tp));
    if (c >= KK) T = Tp;
  }
  int cgt = 0;
#pragma unroll
  for (int k = 0; k < S; ++k) cgt += __popcll(__ballot(u[k] > T));
  const int r = KK - cgt;  // how many value-ties to keep (smallest idx first)
  // idx bisect among equals: largest A with count(eq && idx < A) < r -> A = r-th smallest idx
  int A = 0;
#pragma unroll 1
  for (int bit = 11; bit >= 0; --bit) {
    int Ap = A | (1 << bit);
    int c = 0;
#pragma unroll
    for (int k = 0; k < S; ++k) c += __popcll(__ballot(u[k] == T && si[k] < Ap));
    if (c < r) A = Ap;
  }
  // emit: val > T, or val == T && idx <= A   (exactly KK entries)
  int base = 0;
#pragma unroll
  for (int k = 0; k < S; ++k) {
    bool kp = (u[k] > T) || (u[k] == T && si[k] <= A);
    unsigned long long mk = __ballot(kp);
    int pos = base + __popcll(mk & lmask);
    if (kp) outp[pos] = si[k];
    base += __popcll(mk);
  }
  return __ballot(ord_u32(od) >= T) != 0ull;
}

// ---------------- KNN: 8 queries/wave, top-6/lane cascade + ballot-bisect extract ------
// Block = 256 thr = 4 waves; wave owns 8 queries -> 32 queries/block, grid = GN/32.
// Tiles of 512 candidates; lane's 8 m per tile: lane*4+{0..3} and 256+lane*4+{0..3}.
// Per c: 2 scatter ds_read_b128 (cand) + 2 uniform b128 (q) feed 64 FMA.
// Distance fma chain order identical to the validated R1..R5 kernels.
// amdgpu_waves_per_eu(2,2): pin allocator target -> VGPR budget 256, no heuristic spill
// (R4/R5 lesson: occupancy-driven regalloc spilled the selection state to scratch).
// Exactness: od tracks the best value dropped off a lane's cascade; query is flagged
// for exact cleanup only if od could reach the top-20 (ord(od) >= T).
template<int C>
__global__ void __launch_bounds__(256)
__attribute__((amdgpu_waves_per_eu(2, 2)))
knn4_kernel(const float* __restrict__ x, int bstride,
            const float* __restrict__ xxb,
            int* __restrict__ idx_out,
            int* __restrict__ flag_cnt,
            int* __restrict__ flag_list) {
  constexpr int CC = (C < 16) ? C : 16;
  constexpr int S = 6;
  __shared__ float cand[CC][512];
  __shared__ float q_lds[CC][32];
  __shared__ float xm_lds[512];
  __shared__ float xq_lds[32];
  const int tid = threadIdx.x;
  const int wq = tid >> 6, lane = tid & 63;
  const unsigned long long lmask = (1ull << lane) - 1ull;
  const int qb = blockIdx.x;
  const int b = qb >> 7, n0 = (qb & 127) << 5;
  const float* xb  = x + (size_t)b*bstride;
  const float* xxr = xxb + b*NN;

  if (tid < 32) xq_lds[tid] = xxr[n0 + tid];
  __syncthreads();
  float xq[8];
#pragma unroll
  for (int i = 0; i < 8; ++i) xq[i] = xq_lds[wq*8 + i];

  float sv[8][S]; int si[8][S]; float od[8];
#pragma unroll
  for (int i = 0; i < 8; ++i) {
    od[i] = -INFINITY;
#pragma unroll
    for (int k = 0; k < S; ++k) { sv[i][k] = -INFINITY; si[i][k] = 0x7fffffff; }
  }

  for (int t = 0; t < NN/512; ++t) {
    const int mt0 = t*512;
    float acc[8][8];
#pragma unroll
    for (int i = 0; i < 8; ++i)
#pragma unroll
      for (int j = 0; j < 8; ++j) acc[i][j] = 0.f;

    for (int cc0 = 0; cc0 < C; cc0 += CC) {
      __syncthreads();
      for (int v = tid; v < CC*128; v += 256) {
        int c = v >> 7, mc = (v & 127) * 4;
        *reinterpret_cast<float4*>(&cand[c][mc]) =
          *reinterpret_cast<const float4*>(&xb[(size_t)(cc0 + c)*NN + mt0 + mc]);
      }
      for (int v = tid; v < CC*32; v += 256) {
        int c = v >> 5, qi = v & 31;
        q_lds[c][qi] = xb[(size_t)(cc0 + c)*NN + n0 + qi];
      }
      if (cc0 == 0 && tid < 128)
        *reinterpret_cast<float4*>(&xm_lds[tid*4]) =
          *reinterpret_cast<const float4*>(&xxr[mt0 + tid*4]);
      __syncthreads();
#pragma unroll 8
      for (int c = 0; c < CC; ++c) {
        float4 qa  = *reinterpret_cast<const float4*>(&q_lds[c][wq*8]);     // uniform -> broadcast
        float4 qb2 = *reinterpret_cast<const float4*>(&q_lds[c][wq*8 + 4]); // uniform -> broadcast
        float4 ca  = *reinterpret_cast<const float4*>(&cand[c][lane*4]);
        float4 cb  = *reinterpret_cast<const float4*>(&cand[c][256 + lane*4]);
        float qq[8] = {qa.x, qa.y, qa.z, qa.w, qb2.x, qb2.y, qb2.z, qb2.w};
        float mm[8] = {ca.x, ca.y, ca.z, ca.w, cb.x, cb.y, cb.z, cb.w};
#pragma unroll
        for (int i = 0; i < 8; ++i)
#pragma unroll
          for (int j = 0; j < 8; ++j) acc[i][j] = fmaf(qq[i], mm[j], acc[i][j]);
      }
    }

    float4 xma = *reinterpret_cast<const float4*>(&xm_lds[lane*4]);
    float4 xmb = *reinterpret_cast<const float4*>(&xm_lds[256 + lane*4]);
    float xmv[8] = {xma.x, xma.y, xma.z, xma.w, xmb.x, xmb.y, xmb.z, xmb.w};

#pragma unroll
    for (int i = 0; i < 8; ++i) {
#pragma unroll
      for (int j = 0; j < 8; ++j) {
        const float d = 2.f*acc[i][j] - xq[i] - xmv[j];
        const int mi = mt0 + ((j < 4) ? (lane*4 + j) : (256 + lane*4 + (j - 4)));
        // branchless sorted insert (desc; strict > keeps earlier=smaller idx first on ties)
        bool c0 = d > sv[i][0], c1 = d > sv[i][1], c2 = d > sv[i][2];
        bool c3 = d > sv[i][3], c4 = d > sv[i][4], c5 = d > sv[i][5];
        od[i] = c5 ? fmaxf(od[i], sv[i][5]) : od[i];   // record best dropped value
        sv[i][5] = c4 ? sv[i][4] : (c5 ? d : sv[i][5]);  si[i][5] = c4 ? si[i][4] : (c5 ? mi : si[i][5]);
        sv[i][4] = c3 ? sv[i][3] : (c4 ? d : sv[i][4]);  si[i][4] = c3 ? si[i][3] : (c4 ? mi : si[i][4]);
        sv[i][3] = c2 ? sv[i][2] : (c3 ? d : sv[i][3]);  si[i][3] = c2 ? si[i][2] : (c3 ? mi : si[i][3]);
        sv[i][2] = c1 ? sv[i][1] : (c2 ? d : sv[i][2]);  si[i][2] = c1 ? si[i][1] : (c2 ? mi : si[i][2]);
        sv[i][1] = c0 ? sv[i][0] : (c1 ? d : sv[i][1]);  si[i][1] = c0 ? si[i][0] : (c1 ? mi : si[i][1]);
        sv[i][0] = c0 ? d : sv[i][0];                    si[i][0] = c0 ? mi : si[i][0];
      }
    }
  }

  // extraction: fully unrolled over the 8 queries (static register indexing)
#pragma unroll
  for (int i = 0; i < 8; ++i) {
    const int q = n0 + wq*8 + i;
    int* outp = idx_out + (size_t)(b*NN + q)*KK;
    bool need_fix = extract_top20<S>(sv[i], si[i], od[i], outp, lmask);
    if (need_fix) {
      if (lane == 0) { int p = atomicAdd(flag_cnt, 1); flag_list[p & 4095] = b*NN + q; }
    }
  }
}

// ---------------- exact cleanup for flagged queries (rare; ~1 block per query) ------
template<int C>
__global__ void __launch_bounds__(256) knn_fix_kernel(const float* __restrict__ x, int bstride,
                                                      const float* __restrict__ xxb,
                                                      const int* __restrict__ flag_cnt,
                                                      const int* __restrict__ flag_list,
                                                      int* __restrict__ idx_out) {
  __shared__ float redv[4]; __shared__ int redi[4];
  const int tid = threadIdx.x;
  const int wid = tid >> 6, lane = tid & 63;
  const int cnt = flag_cnt[0] < 4096 ? flag_cnt[0] : 4096;
  for (int f = blockIdx.x; f < cnt; f += gridDim.x) {
    const int qn = flag_list[f];
    const int b = qn >> 12, n = qn & (NN-1);
    const float* xb  = x + (size_t)b*bstride;
    const float* xxr = xxb + b*NN;
    float acc[16];
#pragma unroll
    for (int jj = 0; jj < 16; ++jj) acc[jj] = 0.f;
    for (int c = 0; c < C; ++c) {
      const float qc = xb[(size_t)c*NN + n];
      const float* row = xb + (size_t)c*NN + tid;
#pragma unroll
      for (int jj = 0; jj < 16; ++jj) acc[jj] = fmaf(qc, row[256*jj], acc[jj]);
    }
    const float xq = xxr[n];
    float dv[16]; int di[16]; unsigned used = 0;
#pragma unroll
    for (int jj = 0; jj < 16; ++jj) {
      dv[jj] = 2.f*acc[jj] - xq - xxr[tid + 256*jj];
      di[jj] = tid + 256*jj;
    }
    for (int r = 0; r < KK; ++r) {
      float bv = -INFINITY; int bi = 0x7fffffff;
#pragma unroll
      for (int jj = 0; jj < 16; ++jj) {
        bool ok = !((used >> jj) & 1);
        bool bet = ok && (dv[jj] > bv || (dv[jj] == bv && di[jj] < bi));
        bv = bet ? dv[jj] : bv; bi = bet ? di[jj] : bi;
      }
#pragma unroll
      for (int s = 1; s < 64; s <<= 1) {
        float ov = __shfl_xor(bv, s, 64);
        int   oi = __shfl_xor(bi, s, 64);
        if (ov > bv || (ov == bv && oi < bi)) { bv = ov; bi = oi; }
      }
      if (lane == 0) { redv[wid] = bv; redi[wid] = bi; }
      __syncthreads();
#pragma unroll
      for (int w = 0; w < 4; ++w) {
        float ov = redv[w]; int oi = redi[w];
        if (ov > bv || (ov == bv && oi < bi)) { bv = ov; bi = oi; }
      }
      __syncthreads();
      if ((bi & 255) == tid) used |= 1u << (bi >> 8);
      if (tid == 0) idx_out[(size_t)qn*KK + r] = bi;
    }
  }
}

// ---------------- P = W1 . x,  Q = (W2-W1) . x   (both [b][n][o]) ----------------
template<int C, int O>
__global__ void __launch_bounds__(256) pq_kernel(const float* __restrict__ x, int bstride,
                                                 const float* __restrict__ W,
                                                 float* __restrict__ P, float* __restrict__ Q) {
  constexpr int CC = (C < 32) ? C : 32;
  constexpr int NPP = 256 / O;
  constexpr int NITER = 64 / NPP;
  __shared__ float xt[C*64];
  __shared__ float w1t[CC*O];
  __shared__ float wdt[CC*O];
  const int tid = threadIdx.x;
  const int g0 = blockIdx.x*64;
  const int b = g0 >> 12, n0 = g0 & (NN-1);
  for (int i = tid; i < C*64; i += 256) {
    int c = i >> 6, j = i & 63;
    xt[i] = x[(size_t)b*bstride + (size_t)c*NN + (n0 + j)];
  }
  const int o = tid % O;
  const int ns = tid / O;
  float ap[NITER], aq[NITER];
#pragma unroll
  for (int i = 0; i < NITER; ++i) { ap[i] = 0.f; aq[i] = 0.f; }
  for (int cc = 0; cc < C; cc += CC) {
    __syncthreads();
    for (int i = tid; i < CC*O; i += 256) {
      int oo = i % O, c = i / O;
      float w1 = W[oo*(2*C) + cc + c];
      float w2 = W[oo*(2*C) + C + cc + c];
      w1t[c*O + oo] = w1;
      wdt[c*O + oo] = w2 - w1;
    }
    __syncthreads();
#pragma unroll
    for (int np = 0; np < NITER; ++np) {
      const int nl = np*NPP + ns;
#pragma unroll
      for (int c = 0; c < CC; ++c) {
        float xv = xt[(cc + c)*64 + nl];
        ap[np] = fmaf(xv, w1t[c*O + o], ap[np]);
        aq[np] = fmaf(xv, wdt[c*O + o], aq[np]);
      }
    }
  }
#pragma unroll
  for (int np = 0; np < NITER; ++np) {
    const int nl = np*NPP + ns;
    size_t row = (size_t)(g0 + nl)*O + o;
    P[row] = ap[np];
    Q[row] = aq[np];
  }
}

// ---------------- y = P[m]+Q[n]: per-(b,n,o) max/min over k + per-channel partial sums ----
template<int O>
__global__ void __launch_bounds__(256) stats_kernel(const float* __restrict__ P,
                                                    const float* __restrict__ Q,
                                                    const int* __restrict__ idxb,
                                                    float* __restrict__ ymax,
                                                    float* __restrict__ ymin,
                                                    float* __restrict__ parts) {
  constexpr int NPB = 256 / O;
  __shared__ float ls[256], ls2[256];
  const int tid = threadIdx.x;
  const int o = tid % O, ns = tid / O;
  const int g = blockIdx.x*NPB + ns;
  const int b = g >> 12;
  const float qvv = Q[(size_t)g*O + o];
  const int* ip = idxb + (size_t)g*KK;
  const float* Pb = P + (size_t)b*NN*O;
  float s = 0.f, s2 = 0.f, mx = -INFINITY, mn = INFINITY;
#pragma unroll 4
  for (int k = 0; k < KK; ++k) {
    int m = ip[k];
    float yv = Pb[(size_t)m*O + o] + qvv;
    s += yv; s2 = fmaf(yv, yv, s2);
    mx = fmaxf(mx, yv); mn = fminf(mn, yv);
  }
  ymax[(size_t)g*O + o] = mx;
  ymin[(size_t)g*O + o] = mn;
  ls[tid] = s; ls2[tid] = s2;
  __syncthreads();
  if (ns == 0) {
#pragma unroll
    for (int j = 1; j < NPB; ++j) { s += ls[j*O + o]; s2 += ls2[j*O + o]; }
    parts[(size_t)blockIdx.x*2*O + o] = s;
    parts[(size_t)blockIdx.x*2*O + O + o] = s2;
  }
}

// ---------------- per-channel BN affine coefficients (deterministic f64 tree) ----------
template<int O>
__global__ void __launch_bounds__(256) reduce_kernel(const float* __restrict__ parts, int nblocks,
                                                     const float* __restrict__ gg,
                                                     const float* __restrict__ bbp,
                                                     float* __restrict__ chan) {
  __shared__ double sh[512];
  const int o = blockIdx.x, t = threadIdx.x;
  double S = 0.0, S2 = 0.0;
  for (int i = t; i < nblocks; i += 256) {
    S  += (double)parts[(size_t)i*2*O + o];
    S2 += (double)parts[(size_t)i*2*O + O + o];
  }
  sh[t] = S; sh[256+t] = S2;
  __syncthreads();
  for (int s = 128; s > 0; s >>= 1) {
    if (t < s) { sh[t] += sh[t+s]; sh[256+t] += sh[256+t+s]; }
    __syncthreads();
  }
  if (t == 0) {
    const double M = (double)BB*NN*KK;
    double mean = sh[0]/M;
    double var  = sh[256]/M - mean*mean;
    double inv  = 1.0/sqrt(var + 1e-5);
    double A  = (double)gg[o]*inv;
    double Bc = (double)bbp[o] - mean*A;
    chan[2*o]   = (float)A;
    chan[2*o+1] = (float)Bc;
  }
}

// ---------------- out[b][cbase+o][n] = leaky(A*(A>0?ymax:ymin)+Bc), LDS transpose ------
template<int O>
__global__ void __launch_bounds__(256) final_kernel(const float* __restrict__ ymax,
                                                    const float* __restrict__ ymin,
                                                    const float* __restrict__ chan,
                                                    float* __restrict__ out, int cbase) {
  __shared__ float buf[64*(O+1)];
  const int tid = threadIdx.x;
  const int g0 = blockIdx.x*64;
  const int b = g0 >> 12, n0 = g0 & (NN-1);
  for (int i = tid; i < 64*O; i += 256) {
    int o = i % O, nl = i / O;
    size_t r = (size_t)(g0 + nl)*O + o;
    float A = chan[2*o], Bc = chan[2*o+1];
    float v = (A > 0.f) ? ymax[r] : ymin[r];
    float y = fmaf(A, v, Bc);
    buf[nl*(O+1) + o] = (y > 0.f) ? y : 0.2f*y;
  }
  __syncthreads();
  for (int i = tid; i < 64*O; i += 256) {
    int nl = i & 63, o = i >> 6;
    out[(size_t)b*(OUTC*NN) + (size_t)(cbase + o)*NN + (n0 + nl)] = buf[nl*(O+1) + o];
  }
}

extern "C" void kernel_launch(void* const* d_in, const int* in_sizes, int n_in,
                              void* d_out, int out_size, void* d_ws, size_t ws_size,
                              hipStream_t stream) {
  (void)in_sizes; (void)n_in; (void)out_size; (void)ws_size;
  const float* x  = (const float*)d_in[0];
  const float* W0 = (const float*)d_in[1];
  const float* g0 = (const float*)d_in[2];
  const float* b0 = (const float*)d_in[3];
  const float* W1 = (const float*)d_in[4];
  const float* g1 = (const float*)d_in[5];
  const float* b1 = (const float*)d_in[6];
  const float* W2 = (const float*)d_in[7];
  const float* g2 = (const float*)d_in[8];
  const float* b2 = (const float*)d_in[9];
  float* out = (float*)d_out;
  char* ws = (char*)d_ws;

  float* xxb  = (float*)(ws);                       // 64 KB
  int*   idxb = (int*)  (ws + ((size_t)1<<20));     // 1.31 MB
  float* P    = (float*)(ws + ((size_t)4<<20));     // 8 MB
  float* Q    = (float*)(ws + ((size_t)12<<20));    // 8 MB
  float* ymax = (float*)(ws + ((size_t)20<<20));    // 8 MB
  float* ymin = (float*)(ws + ((size_t)28<<20));    // 8 MB
  float* prts = (float*)(ws + ((size_t)36<<20));    // 8 MB
  float* chan = (float*)(ws + ((size_t)44<<20));    // 1 KB
  int*   fcnt = (int*)  (ws + ((size_t)45<<20));    // 3 ints
  int*   flst = (int*)  (ws + ((size_t)45<<20) + 64); // 3*4096 ints

  hipMemsetAsync(fcnt, 0, 3*sizeof(int), stream);

  // ---- layer 0: C=3 -> O=64, out channels [0,64) ----
  xx_kernel<3><<<GN/256, 256, 0, stream>>>(x, 3*NN, xxb);
  knn4_kernel<3><<<GN/32, 256, 0, stream>>>(x, 3*NN, xxb, idxb, fcnt+0, flst+0*4096);
  knn_fix_kernel<3><<<64, 256, 0, stream>>>(x, 3*NN, xxb, fcnt+0, flst+0*4096, idxb);
  pq_kernel<3,64><<<GN/64, 256, 0, stream>>>(x, 3*NN, W0, P, Q);
  stats_kernel<64><<<GN/4, 256, 0, stream>>>(P, Q, idxb, ymax, ymin, prts);
  reduce_kernel<64><<<64, 256, 0, stream>>>(prts, GN/4, g0, b0, chan);
  final_kernel<64><<<GN/64, 256, 0, stream>>>(ymax, ymin, chan, out, 0);

  // ---- layer 1: C=64 -> O=64, input = out[:,0:64,:], out channels [64,128) ----
  const float* x1 = out;
  xx_kernel<64><<<GN/256, 256, 0, stream>>>(x1, OUTC*NN, xxb);
  knn4_kernel<64><<<GN/32, 256, 0, stream>>>(x1, OUTC*NN, xxb, idxb, fcnt+1, flst+1*4096);
  knn_fix_kernel<64><<<64, 256, 0, stream>>>(x1, OUTC*NN, xxb, fcnt+1, flst+1*4096, idxb);
  pq_kernel<64,64><<<GN/64, 256, 0, stream>>>(x1, OUTC*NN, W1, P, Q);
  stats_kernel<64><<<GN/4, 256, 0, stream>>>(P, Q, idxb, ymax, ymin, prts);
  reduce_kernel<64><<<64, 256, 0, stream>>>(prts, GN/4, g1, b1, chan);
  final_kernel<64><<<GN/64, 256, 0, stream>>>(ymax, ymin, chan, out, 64);

  // ---- layer 2: C=64 -> O=128, input = out[:,64:128,:], out channels [128,256) ----
  const float* x2 = out + (size_t)64*NN;
  xx_kernel<64><<<GN/256, 256, 0, stream>>>(x2, OUTC*NN, xxb);
  knn4_kernel<64><<<GN/32, 256, 0, stream>>>(x2, OUTC*NN, xxb, idxb, fcnt+2, flst+2*4096);
  knn_fix_kernel<64><<<64, 256, 0, stream>>>(x2, OUTC*NN, xxb, fcnt+2, flst+2*4096, idxb);
  pq_kernel<64,128><<<GN/64, 256, 0, stream>>>(x2, OUTC*NN, W2, P, Q);
  stats_kernel<128><<<GN/2, 256, 0, stream>>>(P, Q, idxb, ymax, ymin, prts);
  reduce_kernel<128><<<128, 256, 0, stream>>>(prts, GN/2, g2, b2, chan);
  final_kernel<128><<<GN/64, 256, 0, stream>>>(ymax, ymin, chan, out, 128);
}